// Round 11
// baseline (22.795 us; speedup 1.0000x reference)
//
#include <hip/hip_runtime.h>

// Sequential implicit-midpoint solve: y_k = y_{k-1} + DT*f_k - DT*tanh(W s_k),
// s_k = (y_k + y_{k-1})/2. NFP=1 fixed-point with carried-tanh predictor and
// 2-step speculative pipeline (R8/R10-proven math, absmax 0.022).
//
// R11: 4 cooperative waves per batch chain (256 threads/block) to break the
// solo-wave latency chain (R10: ~1557 cyc/pair, all serial latency).
//   - wave w owns W rows 16w..16w+16; lane l handles row 16w+(l&15),
//     cols 16g..16g+16 (g=l>>4): 8 fdot2 per chain per lane.
//   - state y/f/tcar fully REPLICATED in all 4 waves (bit-identical compute),
//     so only ONE barrier per pair: the partial-sum exchange.
//   - s distribution: each wave writes its OWN private LDS copy and reads it
//     back (in-wave DS in-order + compiler fences, R10-proven) -- no barrier.
//   - partials: lane writes float2(pA,pB) for (row,chunk); after the barrier
//     every lane reads its component's 4 partials as 2x b128 and finishes
//     tanh + update locally. Partial buffer parity-double-buffered.
//   - raw s_barrier with hand s_waitcnt lgkmcnt(0) (NOT vmcnt) so the global
//     f-prefetch stays in flight across barriers.
// W pre-scaled by 2*log2(e): tanh(Ws) = 1 - 2/(exp2(u)+1).

#define SDIM 64
#define NW 4
#define DT_C 0.05f
#define WSCALE 2.8853900817779268f  // 2*log2(e)

typedef _Float16 h2 __attribute__((ext_vector_type(2)));  // fdot2 operand type
typedef __fp16   g2 __attribute__((ext_vector_type(2)));  // cvt_pkrtz return type
union H2U { int i; h2 h; g2 g; };

__device__ __forceinline__ float recip_fast(float x) {
    float r;
    asm("v_rcp_f32 %0, %1" : "=v"(r) : "v"(x));
    return r;
}

__device__ __forceinline__ float exp2_fast(float x) {
    float r;
    asm("v_exp_f32 %0, %1" : "=v"(r) : "v"(x));
    return r;
}

__device__ __forceinline__ h2 pack_h2(float a, float b) {
    H2U u; u.g = __builtin_amdgcn_cvt_pkrtz(a, b); return u.h;
}
__device__ __forceinline__ h2 int_as_h2(int v) {
    H2U u; u.i = v; return u.h;
}
__device__ __forceinline__ int h2_as_int(h2 v) {
    H2U u; u.h = v; return u.i;
}

// Cooperative double matvec: on entry lane l (all waves) holds sA_l, sB_l.
// On exit lane l (all waves) holds uA_l = (W sA)_l, uB_l = (W sB)_l.
// lds_sw = this wave's private 64-dword s buffer; pbuf = parity-selected
// partial buffer (256 float2: slot row*4+g); wp2 = this lane's 8 packed
// W pairs (row 16*wid+(l&15), cols 16g..16g+16).
__device__ __forceinline__ void matvec2_mw(int* lds_sw, float2* pbuf,
                                           const h2* __restrict__ wp2,
                                           int l, int wid,
                                           float sA, float sB,
                                           float& uA, float& uB)
{
    // pack (s[2m], s[2m+1]) pairs; interleave A/B by lane parity (R10 layout)
    const int sbA = __float_as_int(sA);
    const int nbA = __builtin_amdgcn_update_dpp(0, sbA, 0xB1, 0xF, 0xF, true);
    const int sbB = __float_as_int(sB);
    const int nbB = __builtin_amdgcn_update_dpp(0, sbB, 0xB1, 0xF, 0xF, true);
    const int pkA  = h2_as_int(pack_h2(sA, __int_as_float(nbA)));
    const int pkBs = h2_as_int(pack_h2(__int_as_float(nbB), sB));

    // dword 2m = A-pair m, dword 2m+1 = B-pair m (own-wave private copy)
    lds_sw[l] = (l & 1) ? pkBs : pkA;
    asm volatile("" ::: "memory");
    __builtin_amdgcn_sched_barrier(0);

    const int g = l >> 4;
    const int4* q4 = reinterpret_cast<const int4*>(lds_sw);
    const int4 q0 = q4[4 * g + 0];
    const int4 q1 = q4[4 * g + 1];
    const int4 q2 = q4[4 * g + 2];
    const int4 q3 = q4[4 * g + 3];

    float a0 = 0.f, a1 = 0.f, b0 = 0.f, b1 = 0.f;
    a0 = __builtin_amdgcn_fdot2(wp2[0], int_as_h2(q0.x), a0, false);
    b0 = __builtin_amdgcn_fdot2(wp2[0], int_as_h2(q0.y), b0, false);
    a1 = __builtin_amdgcn_fdot2(wp2[1], int_as_h2(q0.z), a1, false);
    b1 = __builtin_amdgcn_fdot2(wp2[1], int_as_h2(q0.w), b1, false);
    a0 = __builtin_amdgcn_fdot2(wp2[2], int_as_h2(q1.x), a0, false);
    b0 = __builtin_amdgcn_fdot2(wp2[2], int_as_h2(q1.y), b0, false);
    a1 = __builtin_amdgcn_fdot2(wp2[3], int_as_h2(q1.z), a1, false);
    b1 = __builtin_amdgcn_fdot2(wp2[3], int_as_h2(q1.w), b1, false);
    a0 = __builtin_amdgcn_fdot2(wp2[4], int_as_h2(q2.x), a0, false);
    b0 = __builtin_amdgcn_fdot2(wp2[4], int_as_h2(q2.y), b0, false);
    a1 = __builtin_amdgcn_fdot2(wp2[5], int_as_h2(q2.z), a1, false);
    b1 = __builtin_amdgcn_fdot2(wp2[5], int_as_h2(q2.w), b1, false);
    a0 = __builtin_amdgcn_fdot2(wp2[6], int_as_h2(q3.x), a0, false);
    b0 = __builtin_amdgcn_fdot2(wp2[6], int_as_h2(q3.y), b0, false);
    a1 = __builtin_amdgcn_fdot2(wp2[7], int_as_h2(q3.z), a1, false);
    b1 = __builtin_amdgcn_fdot2(wp2[7], int_as_h2(q3.w), b1, false);
    const float pA = a0 + a1;
    const float pB = b0 + b1;

    // partial for (row R, chunk g) at slot R*4+g
    const int R = (wid << 4) | (l & 15);
    pbuf[R * 4 + g] = make_float2(pA, pB);

    // drain DS (write visible) WITHOUT draining vmcnt (keep f-prefetch async)
    asm volatile("s_waitcnt lgkmcnt(0)" ::: "memory");
    __builtin_amdgcn_s_barrier();
    asm volatile("" ::: "memory");
    __builtin_amdgcn_sched_barrier(0);

    // lane l gathers its component's 4 partials: slots 4l..4l+3 = 2x b128
    const int4* p4 = reinterpret_cast<const int4*>(pbuf);
    const int4 u0 = p4[2 * l + 0];
    const int4 u1 = p4[2 * l + 1];
    uA = (__int_as_float(u0.x) + __int_as_float(u0.z)) +
         (__int_as_float(u1.x) + __int_as_float(u1.z));
    uB = (__int_as_float(u0.y) + __int_as_float(u0.w)) +
         (__int_as_float(u1.y) + __int_as_float(u1.w));
}

__global__ __launch_bounds__(NW * 64) void rnes_mw_kernel(
    const float* __restrict__ y0,
    const float* __restrict__ forces,
    const float* __restrict__ W,
    float* __restrict__ out,
    int n, int B)
{
    const int b   = blockIdx.x;
    const int tid = threadIdx.x;
    const int wid = tid >> 6;
    const int l   = tid & 63;   // lane = state component (replicated per wave)
    const int g   = l >> 4;
    const int R   = (wid << 4) | (l & 15);  // owned W row

    // W fragment: row R, cols 16g..16g+16 -> 8 half2, pre-scaled by 2*log2(e)
    h2 wp2[8];
    {
        const float4* Wr = reinterpret_cast<const float4*>(W + R * SDIM + g * 16);
        #pragma unroll
        for (int j4 = 0; j4 < 4; ++j4) {
            float4 v = Wr[j4];
            wp2[2 * j4 + 0] = pack_h2(WSCALE * v.x, WSCALE * v.y);
            wp2[2 * j4 + 1] = pack_h2(WSCALE * v.z, WSCALE * v.w);
        }
    }

    __shared__ __align__(16) int    lds_s[NW * SDIM];        // per-wave s copies
    __shared__ __align__(16) float2 lds_p[2][NW * SDIM];     // partials, dbuf

    int* lds_sw = lds_s + (wid << 6);

    const size_t stride = (size_t)B * SDIM;
    const int off = b * SDIM + l;

    float yprev = y0[off];
    if (wid == 0) out[off] = yprev;  // out[0] = y0 pass-through

    // Seed tanh carry at s ~= y0
    float uA, uB, tcar;
    matvec2_mw(lds_sw, lds_p[0], wp2, l, wid, yprev, yprev, uA, uB);
    tcar = fmaf(-2.0f, recip_fast(exp2_fast(uA) + 1.0f), 1.0f);

    // force ring: fA=f_k .. fD=f_{k+3} (replicated loads in all waves)
    float fA = (n > 1) ? forces[1 * stride + off] : 0.f;
    float fB = (n > 2) ? forces[2 * stride + off] : 0.f;
    float fC = (n > 3) ? forces[3 * stride + off] : 0.f;
    float fD = (n > 4) ? forces[4 * stride + off] : 0.f;
    const float* fpre = forces + 5 * stride + off;
    float* op = out + stride + off;

    int parity = 1;
    int k = 1;
    #pragma unroll 1
    for (; k + 1 < n; k += 2) {
        float fE = 0.f, fF = 0.f;
        if (k + 4 < n) fE = fpre[0];
        if (k + 5 < n) fF = fpre[stride];
        fpre += 2 * stride;

        const float ypA = fmaf(DT_C, fA - tcar, yprev);         // y_pred_k
        const float sA  = fmaf(0.5f * DT_C, fA - tcar, yprev);  // exact midpoint
        const float sB  = fmaf(0.5f * DT_C, fB - tcar, ypA);    // speculative midpoint

        matvec2_mw(lds_sw, lds_p[parity], wp2, l, wid, sA, sB, uA, uB);

        const float rA = recip_fast(exp2_fast(uA) + 1.0f);
        const float rB = recip_fast(exp2_fast(uB) + 1.0f);
        const float yk  = fmaf(2.0f * DT_C, rA, fmaf(DT_C, fA, yprev) - DT_C);
        const float yk1 = fmaf(2.0f * DT_C, rB, fmaf(DT_C, fB, yk) - DT_C);

        if (wid == 0) {
            op[0]      = yk;
            op[stride] = yk1;
        }
        op += 2 * stride;
        yprev = yk1;
        tcar = fmaf(-2.0f, rB, 1.0f);
        fA = fC; fB = fD; fC = fE; fD = fF;
        parity ^= 1;
    }

    // odd tail (not hit for n=65; uniform across block)
    if (k < n) {
        const float sA = fmaf(0.5f * DT_C, fA - tcar, yprev);
        matvec2_mw(lds_sw, lds_p[parity], wp2, l, wid, sA, sA, uA, uB);
        const float rA = recip_fast(exp2_fast(uA) + 1.0f);
        const float yk = fmaf(2.0f * DT_C, rA, fmaf(DT_C, fA, yprev) - DT_C);
        if (wid == 0) *op = yk;
    }
}

extern "C" void kernel_launch(void* const* d_in, const int* in_sizes, int n_in,
                              void* d_out, int out_size, void* d_ws, size_t ws_size,
                              hipStream_t stream) {
    const float* y0     = (const float*)d_in[0];   // (B, S)
    const float* forces = (const float*)d_in[1];   // (n, B, S)
    const float* W      = (const float*)d_in[2];   // (S, S)
    float* out = (float*)d_out;                    // (n, B, S)

    const int BS = in_sizes[0];       // B * S
    const int B  = BS / SDIM;         // 128
    const int n  = in_sizes[1] / BS;  // 65

    rnes_mw_kernel<<<B, NW * 64, 0, stream>>>(y0, forces, W, out, n, B);
}